// Round 5
// baseline (731.775 us; speedup 1.0000x reference)
//
#include <hip/hip_runtime.h>

typedef unsigned short u16;
typedef unsigned int   u32;
typedef _Float16 f16;
typedef __attribute__((ext_vector_type(8))) _Float16 half8;
typedef __attribute__((ext_vector_type(4))) float f32x4;

#define NBATCH 16384

__device__ __forceinline__ u16 f2h(float x) {
  union { f16 h; u16 u; } v; v.h = (f16)x; return v.u;
}

// ---------- prep: transpose fp32 (M x N) -> f16 (N x M), 16 mats (z = layer*2 + net)
__global__ __launch_bounds__(256) void cvt_w(
    const float* __restrict__ tsrc, const float* __restrict__ ssrc,
    u16* __restrict__ dst, int M, int N)
{
  __shared__ float tile[32][33];
  int z = blockIdx.z;
  const float* src = ((z & 1) ? ssrc : tsrc) + (size_t)(z >> 1) * M * N;
  u16* d = dst + (size_t)z * M * N;
  int n0 = blockIdx.x * 32, m0 = blockIdx.y * 32;
  for (int r = 0; r < 4; r++) {
    int m = m0 + threadIdx.y + r * 8, n = n0 + threadIdx.x;
    tile[threadIdx.y + r * 8][threadIdx.x] = src[(size_t)m * N + n];
  }
  __syncthreads();
  for (int r = 0; r < 4; r++) {
    int n = n0 + threadIdx.y + r * 8, m = m0 + threadIdx.x;
    d[(size_t)n * M + m] = f2h(tile[threadIdx.x][threadIdx.y + r * 8]);
  }
}

// ---------- fused RealNVP: 1 block = 64 rows, 512 threads (waves 0-3: t-net, 4-7: s-net).
// Per net one 64x512 f16 LDS buffer, XOR-swizzled 8-elem chunks; H2 overwrites H1 in place.
// z/log_det in registers: thread t owns row (t>>3), cols [(t&7)*8, +8).
__global__ __launch_bounds__(512, 2) void meganvp(
    const float* __restrict__ y,
    const u16* __restrict__ W1T, const u16* __restrict__ W2T, const u16* __restrict__ W3T,
    const float* __restrict__ tb1, const float* __restrict__ sb1,
    const float* __restrict__ tb2, const float* __restrict__ sb2,
    const float* __restrict__ tb3, const float* __restrict__ sb3,
    const float* __restrict__ s_scale, const float* __restrict__ s_shift,
    float* __restrict__ out)
{
  __shared__ u16 bufT[64 * 512];    // 64 KB  t-net H1 then H2 (in place)
  __shared__ u16 bufS[64 * 512];    // 64 KB  s-net
  __shared__ float TS[64 * 68];     // 17 KB  coupling pairs; head of region doubles as X

  const int t = threadIdx.x;
  const int m0 = blockIdx.x * 64;
  const int lane = t & 63, w = t >> 6, lm = lane & 15, quad = lane >> 4;
  const int g = w >> 2, wg = w & 3, cw = wg * 128;
  const int phase = blockIdx.x & 15;
  const int zr = t >> 3, zq = t & 7, c0 = zq * 8;
  u16* X = (u16*)TS;                // X[64][40] f16
  u16* buf = g ? bufS : bufT;

  float z[8], ld[8];
  {
    const float* yb = y + (size_t)(m0 + zr) * 64 + c0;
    f32x4 v0 = *(const f32x4*)&yb[0];
    f32x4 v1 = *(const f32x4*)&yb[4];
#pragma unroll
    for (int k = 0; k < 4; k++) { z[k] = v0[k]; z[4 + k] = v1[k]; }
#pragma unroll
    for (int e = 0; e < 8; e++) ld[e] = 0.f;
  }

  for (int layer = 0; layer < 8; layer++) {
    const int par = layer & 1;
    const int idx = layer * 2 + g;
    __syncthreads();                       // TS reads of prev layer done; X region free
    { // X build: 4 pass-through f16 per thread (j = zq*4 .. +3)
      union { u16 a[4]; uint2 v; } xv;
#pragma unroll
      for (int e = 0; e < 4; e++) xv.a[e] = f2h(z[2 * e + 1 - par]);
      *(uint2*)&X[zr * 40 + zq * 4] = xv.v;
    }
    const float* b1p = (g ? sb1 : tb1) + layer * 512 + cw + lm;
    const float* b2p = (g ? sb2 : tb2) + layer * 512 + cw + lm;
    float bias1[8];
#pragma unroll
    for (int ct = 0; ct < 8; ct++) bias1[ct] = b1p[ct * 16];
    __syncthreads();

    // ---- H1 = relu(X @ W1 + b1), K=32, out cols [cw, cw+128) of net g
    {
      const u16* W1p = W1T + ((size_t)idx * 512 + cw + lm) * 32 + quad * 8;
      half8 bv[8];
#pragma unroll
      for (int ct = 0; ct < 8; ct++) bv[ct] = *(const half8*)&W1p[ct * 512];
      half8 av[4];
#pragma unroll
      for (int rt = 0; rt < 4; rt++)
        av[rt] = *(const half8*)&X[(rt * 16 + lm) * 40 + quad * 8];
      f32x4 zz = {0.f, 0.f, 0.f, 0.f};
      f32x4 acc[4][8];
#pragma unroll
      for (int rt = 0; rt < 4; rt++)
#pragma unroll
        for (int ct = 0; ct < 8; ct++)
          acc[rt][ct] = __builtin_amdgcn_mfma_f32_16x16x32_f16(av[rt], bv[ct], zz, 0, 0, 0);
      // epilogue -> buf (prev H2 fully consumed by heads before top barrier)
#pragma unroll
      for (int rt = 0; rt < 4; rt++) {
        const int mrow = rt * 16 + quad * 4;
#pragma unroll
        for (int ct = 0; ct < 8; ct++) {
          const int n = cw + ct * 16 + lm;
#pragma unroll
          for (int r = 0; r < 4; r++) {
            float v = acc[rt][ct][r] + bias1[ct];
            v = v > 0.f ? v : 0.f;
            const int m = mrow + r;
            buf[m * 512 + ((((n >> 3) ^ (m & 7)) << 3) | (n & 7))] = f2h(v);
          }
        }
      }
    }
    float bias2[8];
#pragma unroll
    for (int ct = 0; ct < 8; ct++) bias2[ct] = b2p[ct * 16];
    __syncthreads();

    // ---- H2 = relu(H1 @ W2 + b2), K=512
    {
      const u16* W2p = W2T + ((size_t)idx * 512 + cw + lm) * 512 + quad * 8;
      f32x4 zz = {0.f, 0.f, 0.f, 0.f};
      f32x4 acc[4][8];
#pragma unroll
      for (int rt = 0; rt < 4; rt++)
#pragma unroll
        for (int ct = 0; ct < 8; ct++) acc[rt][ct] = zz;
#pragma unroll
      for (int ci = 0; ci < 16; ci++) {
        const int kk = ((ci + phase) & 15) * 32;
        half8 bv[8];
#pragma unroll
        for (int ct = 0; ct < 8; ct++) bv[ct] = *(const half8*)&W2p[ct * 8192 + kk];
        half8 av[4];
#pragma unroll
        for (int rt = 0; rt < 4; rt++) {
          const int m = rt * 16 + lm;
          av[rt] = *(const half8*)&buf[m * 512 + ((((kk >> 3) + quad) ^ (m & 7)) << 3)];
        }
#pragma unroll
        for (int rt = 0; rt < 4; rt++)
#pragma unroll
          for (int ct = 0; ct < 8; ct++)
            acc[rt][ct] = __builtin_amdgcn_mfma_f32_16x16x32_f16(av[rt], bv[ct], acc[rt][ct], 0, 0, 0);
      }
      __syncthreads();                     // all H1 reads done -> in-place write legal
#pragma unroll
      for (int rt = 0; rt < 4; rt++) {
        const int mrow = rt * 16 + quad * 4;
#pragma unroll
        for (int ct = 0; ct < 8; ct++) {
          const int n = cw + ct * 16 + lm;
#pragma unroll
          for (int r = 0; r < 4; r++) {
            float v = acc[rt][ct][r] + bias2[ct];
            v = v > 0.f ? v : 0.f;
            const int m = mrow + r;
            buf[m * 512 + ((((n >> 3) ^ (m & 7)) << 3) | (n & 7))] = f2h(v);
          }
        }
      }
    }
    __syncthreads();

    // ---- head: wave handles rows [wg*16, +16) x 32 cols of its net, K=512
    {
      const u16* W3p = W3T + ((size_t)idx * 32 + lm) * 512 + quad * 8;
      f32x4 ha[2][2];
      ha[0][0] = (f32x4){0.f, 0.f, 0.f, 0.f};
      ha[0][1] = ha[0][0]; ha[1][0] = ha[0][0]; ha[1][1] = ha[0][0];
      const int m = wg * 16 + lm;
#pragma unroll
      for (int ci = 0; ci < 16; ci++) {
        const int kk = ((ci + phase) & 15) * 32;
        half8 av = *(const half8*)&buf[m * 512 + ((((kk >> 3) + quad) ^ (m & 7)) << 3)];
        half8 b0 = *(const half8*)&W3p[kk];
        half8 b1 = *(const half8*)&W3p[16 * 512 + kk];
        ha[ci & 1][0] = __builtin_amdgcn_mfma_f32_16x16x32_f16(av, b0, ha[ci & 1][0], 0, 0, 0);
        ha[ci & 1][1] = __builtin_amdgcn_mfma_f32_16x16x32_f16(av, b1, ha[ci & 1][1], 0, 0, 0);
      }
      if (g == 0) {
#pragma unroll
        for (int ct = 0; ct < 2; ct++) {
          const float b3 = tb3[layer * 32 + ct * 16 + lm];
          const int j = ct * 16 + lm;
#pragma unroll
          for (int r = 0; r < 4; r++) {
            const int mm = wg * 16 + quad * 4 + r;
            TS[mm * 68 + 2 * j] = ha[0][ct][r] + ha[1][ct][r] + b3;
          }
        }
      } else {
#pragma unroll
        for (int ct = 0; ct < 2; ct++) {
          const int jj = layer * 32 + ct * 16 + lm;
          const float b3 = sb3[jj], sc = s_scale[jj], sh = s_shift[jj];
          const int j = ct * 16 + lm;
#pragma unroll
          for (int r = 0; r < 4; r++) {
            const int mm = wg * 16 + quad * 4 + r;
            TS[mm * 68 + 2 * j + 1] = tanhf(ha[0][ct][r] + ha[1][ct][r] + b3) * sc + sh;
          }
        }
      }
    }
    __syncthreads();

    // ---- coupling: thread reads its 4 (t,s) pairs, updates z/ld in registers
    {
      const float* base = &TS[zr * 68 + zq * 8];
      f32x4 q0 = *(const f32x4*)&base[0];
      f32x4 q1 = *(const f32x4*)&base[4];
      float q[8];
#pragma unroll
      for (int k = 0; k < 4; k++) { q[k] = q0[k]; q[4 + k] = q1[k]; }
#pragma unroll
      for (int e = 0; e < 4; e++) {
        const float tv = q[2 * e], sv = q[2 * e + 1];
        const int zi = 2 * e + par;
        z[zi] = z[zi] * expf(sv) + tv;
        ld[zi] += sv;
      }
    }
  } // layer

  // ---- store z and log_det
  {
    float* zb = out + (size_t)(m0 + zr) * 64 + c0;
    float* lb = out + (size_t)NBATCH * 64 + (size_t)(m0 + zr) * 64 + c0;
    f32x4 v0, v1, l0, l1;
#pragma unroll
    for (int k = 0; k < 4; k++) {
      v0[k] = z[k]; v1[k] = z[4 + k];
      l0[k] = ld[k]; l1[k] = ld[4 + k];
    }
    *(f32x4*)&zb[0] = v0; *(f32x4*)&zb[4] = v1;
    *(f32x4*)&lb[0] = l0; *(f32x4*)&lb[4] = l1;
  }
}

extern "C" void kernel_launch(void* const* d_in, const int* in_sizes, int n_in,
                              void* d_out, int out_size, void* d_ws, size_t ws_size,
                              hipStream_t stream) {
  (void)in_sizes; (void)n_in; (void)out_size; (void)ws_size;
  const float* y   = (const float*)d_in[0];
  const float* tW1 = (const float*)d_in[1];
  const float* tb1 = (const float*)d_in[2];
  const float* tW2 = (const float*)d_in[3];
  const float* tb2 = (const float*)d_in[4];
  const float* tW3 = (const float*)d_in[5];
  const float* tb3 = (const float*)d_in[6];
  const float* sW1 = (const float*)d_in[7];
  const float* sb1 = (const float*)d_in[8];
  const float* sW2 = (const float*)d_in[9];
  const float* sb2 = (const float*)d_in[10];
  const float* sW3 = (const float*)d_in[11];
  const float* sb3 = (const float*)d_in[12];
  const float* s_scale = (const float*)d_in[13];
  const float* s_shift = (const float*)d_in[14];
  float* out = (float*)d_out;

  char* ws = (char*)d_ws;
  const size_t W1SZ = (size_t)16 * 512 * 32 * 2;    // 524288
  const size_t W2SZ = (size_t)16 * 512 * 512 * 2;   // 8388608
  u16* W1 = (u16*)(ws);
  u16* W2 = (u16*)(ws + W1SZ);
  u16* W3 = (u16*)(ws + W1SZ + W2SZ);

  cvt_w<<<dim3(16, 1, 16), dim3(32, 8), 0, stream>>>(tW1, sW1, W1, 32, 512);
  cvt_w<<<dim3(16, 16, 16), dim3(32, 8), 0, stream>>>(tW2, sW2, W2, 512, 512);
  cvt_w<<<dim3(1, 16, 16), dim3(32, 8), 0, stream>>>(tW3, sW3, W3, 512, 32);

  meganvp<<<256, 512, 0, stream>>>(y, W1, W2, W3, tb1, sb1, tb2, sb2, tb3, sb3,
                                   s_scale, s_shift, out);
}

// Round 6
// 469.780 us; speedup vs baseline: 1.5577x; 1.5577x over previous
//
#include <hip/hip_runtime.h>

typedef unsigned short u16;
typedef unsigned int   u32;
typedef _Float16 f16;
typedef __attribute__((ext_vector_type(8))) _Float16 half8;
typedef __attribute__((ext_vector_type(4))) float f32x4;

#define NBATCH 16384

__device__ __forceinline__ u16 f2h(float x) {
  union { f16 h; u16 u; } v; v.h = (f16)x; return v.u;
}

// ---------- prep: transpose fp32 (M x N) -> f16 (N x M), 16 mats (z = layer*2 + net)
__global__ __launch_bounds__(256) void cvt_w(
    const float* __restrict__ tsrc, const float* __restrict__ ssrc,
    u16* __restrict__ dst, int M, int N)
{
  __shared__ float tile[32][33];
  int z = blockIdx.z;
  const float* src = ((z & 1) ? ssrc : tsrc) + (size_t)(z >> 1) * M * N;
  u16* d = dst + (size_t)z * M * N;
  int n0 = blockIdx.x * 32, m0 = blockIdx.y * 32;
  for (int r = 0; r < 4; r++) {
    int m = m0 + threadIdx.y + r * 8, n = n0 + threadIdx.x;
    tile[threadIdx.y + r * 8][threadIdx.x] = src[(size_t)m * N + n];
  }
  __syncthreads();
  for (int r = 0; r < 4; r++) {
    int n = n0 + threadIdx.y + r * 8, m = m0 + threadIdx.x;
    d[(size_t)n * M + m] = f2h(tile[threadIdx.x][threadIdx.y + r * 8]);
  }
}

// ---------- fused RealNVP: 1 block = 64 rows, 512 threads, 8 waves.
// Nets processed SERIALLY (t then s) to keep the streamed weight working set at
// 512 KB/XCD (R4-measured FETCH=44MB regime). Wave w owns cols [w*64,+64) of the
// 512 hidden features. One in-place 64x512 f16 H buffer (XOR-swizzled chunks).
// z/log_det in registers: thread t owns row (t>>3), cols [(t&7)*8, +8).
__global__ __launch_bounds__(512, 2) void meganvp(
    const float* __restrict__ y,
    const u16* __restrict__ W1T, const u16* __restrict__ W2T, const u16* __restrict__ W3T,
    const float* __restrict__ tb1, const float* __restrict__ sb1,
    const float* __restrict__ tb2, const float* __restrict__ sb2,
    const float* __restrict__ tb3, const float* __restrict__ sb3,
    const float* __restrict__ s_scale, const float* __restrict__ s_shift,
    float* __restrict__ out)
{
  __shared__ u16 buf[64 * 512];     // 64 KB: H1 then H2 in place (per net, serial)
  __shared__ u16 X[64 * 40];        // 5 KB: f16 pass-through half
  __shared__ float TS[64 * 68];     // 17 KB: coupling (t,s) pairs, 16B-aligned rows

  const int t = threadIdx.x;
  const int m0 = blockIdx.x * 64;
  const int lane = t & 63, w = t >> 6, lm = lane & 15, quad = lane >> 4;
  const int cw = w * 64;                       // wave's 64-col slice
  const int phase = blockIdx.x & 15;
  const int zr = t >> 3, zq = t & 7, c0 = zq * 8;

  float z[8], ld[8];
  {
    const float* yb = y + (size_t)(m0 + zr) * 64 + c0;
    f32x4 v0 = *(const f32x4*)&yb[0];
    f32x4 v1 = *(const f32x4*)&yb[4];
#pragma unroll
    for (int k = 0; k < 4; k++) { z[k] = v0[k]; z[4 + k] = v1[k]; }
#pragma unroll
    for (int e = 0; e < 8; e++) ld[e] = 0.f;
  }

  for (int layer = 0; layer < 8; layer++) {
    const int par = layer & 1;
    { // X build: 4 pass-through f16 per thread
      union { u16 a[4]; uint2 v; } xv;
#pragma unroll
      for (int e = 0; e < 4; e++) xv.a[e] = f2h(z[2 * e + 1 - par]);
      *(uint2*)&X[zr * 40 + zq * 4] = xv.v;
    }
    __syncthreads();                          // X visible (also fences prev coupling)

    for (int net = 0; net < 2; net++) {
      const int idx = layer * 2 + net;

      // ---- H1 = relu(X @ W1 + b1), K=32, wave cols [cw, cw+64)
      {
        const float* b1p = (net ? sb1 : tb1) + layer * 512 + cw + lm;
        float bias1[4];
#pragma unroll
        for (int ct = 0; ct < 4; ct++) bias1[ct] = b1p[ct * 16];
        const u16* W1p = W1T + ((size_t)idx * 512 + cw + lm) * 32 + quad * 8;
        half8 bv[4];
#pragma unroll
        for (int ct = 0; ct < 4; ct++) bv[ct] = *(const half8*)&W1p[ct * 512];
        half8 av[4];
#pragma unroll
        for (int rt = 0; rt < 4; rt++)
          av[rt] = *(const half8*)&X[(rt * 16 + lm) * 40 + quad * 8];
        f32x4 zz = {0.f, 0.f, 0.f, 0.f};
        f32x4 acc[4][4];
#pragma unroll
        for (int rt = 0; rt < 4; rt++)
#pragma unroll
          for (int ct = 0; ct < 4; ct++)
            acc[rt][ct] = __builtin_amdgcn_mfma_f32_16x16x32_f16(av[rt], bv[ct], zz, 0, 0, 0);
        // buf is free here: prev contents fully consumed before the last barrier
#pragma unroll
        for (int rt = 0; rt < 4; rt++) {
          const int mrow = rt * 16 + quad * 4;
#pragma unroll
          for (int ct = 0; ct < 4; ct++) {
            const int n = cw + ct * 16 + lm;
#pragma unroll
            for (int r = 0; r < 4; r++) {
              float v = acc[rt][ct][r] + bias1[ct];
              v = v > 0.f ? v : 0.f;
              const int m = mrow + r;
              buf[m * 512 + ((((n >> 3) ^ (m & 7)) << 3) | (n & 7))] = f2h(v);
            }
          }
        }
      }
      __syncthreads();                        // H1 写完 -> H2 reads

      // ---- H2 = relu(H1 @ W2 + b2), K=512, B streamed with depth-2 prefetch
      {
        const float* b2p = (net ? sb2 : tb2) + layer * 512 + cw + lm;
        float bias2[4];
#pragma unroll
        for (int ct = 0; ct < 4; ct++) bias2[ct] = b2p[ct * 16];
        const u16* W2p = W2T + ((size_t)idx * 512 + cw + lm) * 512 + quad * 8;
        f32x4 zz = {0.f, 0.f, 0.f, 0.f};
        f32x4 acc[4][4];
#pragma unroll
        for (int rt = 0; rt < 4; rt++)
#pragma unroll
          for (int ct = 0; ct < 4; ct++) acc[rt][ct] = zz;
        half8 bb[2][4];
        {
          const int kk0 = (phase & 15) * 32, kk1 = ((phase + 1) & 15) * 32;
#pragma unroll
          for (int ct = 0; ct < 4; ct++) {
            bb[0][ct] = *(const half8*)&W2p[ct * 8192 + kk0];
            bb[1][ct] = *(const half8*)&W2p[ct * 8192 + kk1];
          }
        }
#pragma unroll
        for (int ci = 0; ci < 16; ci++) {
          const int kk = ((ci + phase) & 15) * 32;
          half8 av[4];
#pragma unroll
          for (int rt = 0; rt < 4; rt++) {
            const int m = rt * 16 + lm;
            av[rt] = *(const half8*)&buf[m * 512 + ((((kk >> 3) + quad) ^ (m & 7)) << 3)];
          }
          half8 cur[4];
#pragma unroll
          for (int ct = 0; ct < 4; ct++) cur[ct] = bb[ci & 1][ct];
          if (ci < 14) {
            const int kn = ((ci + 2 + phase) & 15) * 32;
#pragma unroll
            for (int ct = 0; ct < 4; ct++)
              bb[ci & 1][ct] = *(const half8*)&W2p[ct * 8192 + kn];
          }
#pragma unroll
          for (int rt = 0; rt < 4; rt++)
#pragma unroll
            for (int ct = 0; ct < 4; ct++)
              acc[rt][ct] = __builtin_amdgcn_mfma_f32_16x16x32_f16(av[rt], cur[ct], acc[rt][ct], 0, 0, 0);
        }
        __syncthreads();                      // all H1 reads done -> in-place write legal
#pragma unroll
        for (int rt = 0; rt < 4; rt++) {
          const int mrow = rt * 16 + quad * 4;
#pragma unroll
          for (int ct = 0; ct < 4; ct++) {
            const int n = cw + ct * 16 + lm;
#pragma unroll
            for (int r = 0; r < 4; r++) {
              float v = acc[rt][ct][r] + bias2[ct];
              v = v > 0.f ? v : 0.f;
              const int m = mrow + r;
              buf[m * 512 + ((((n >> 3) ^ (m & 7)) << 3) | (n & 7))] = f2h(v);
            }
          }
        }
      }
      __syncthreads();                        // H2 visible -> head reads

      // ---- head: wave w -> rows [(w&3)*16,+16), col tile (w>>2)*16, K=512
      {
        const int hr = (w & 3) * 16, hc = (w >> 2) * 16;
        const u16* W3p = W3T + ((size_t)idx * 32 + hc + lm) * 512 + quad * 8;
        f32x4 ha[2];
        ha[0] = (f32x4){0.f, 0.f, 0.f, 0.f}; ha[1] = ha[0];
        const int m = hr + lm;
#pragma unroll
        for (int ci = 0; ci < 16; ci++) {
          const int kk = ((ci + phase) & 15) * 32;
          half8 av = *(const half8*)&buf[m * 512 + ((((kk >> 3) + quad) ^ (m & 7)) << 3)];
          half8 bv = *(const half8*)&W3p[kk];
          ha[ci & 1] = __builtin_amdgcn_mfma_f32_16x16x32_f16(av, bv, ha[ci & 1], 0, 0, 0);
        }
        const int j = hc + lm;
        if (net == 0) {
          const float b3 = tb3[layer * 32 + j];
#pragma unroll
          for (int r = 0; r < 4; r++) {
            const int mm = hr + quad * 4 + r;
            TS[mm * 68 + 2 * j] = ha[0][r] + ha[1][r] + b3;
          }
        } else {
          const int jj = layer * 32 + j;
          const float b3 = sb3[jj], sc = s_scale[jj], sh = s_shift[jj];
#pragma unroll
          for (int r = 0; r < 4; r++) {
            const int mm = hr + quad * 4 + r;
            TS[mm * 68 + 2 * j + 1] = tanhf(ha[0][r] + ha[1][r] + b3) * sc + sh;
          }
        }
      }
      __syncthreads();                        // head buf-reads done -> next H1 write; TS visible
    } // net

    // ---- coupling: thread reads its 4 (t,s) pairs, updates z/ld in registers
    {
      const float* base = &TS[zr * 68 + zq * 8];
      f32x4 q0 = *(const f32x4*)&base[0];
      f32x4 q1 = *(const f32x4*)&base[4];
      float q[8];
#pragma unroll
      for (int k = 0; k < 4; k++) { q[k] = q0[k]; q[4 + k] = q1[k]; }
#pragma unroll
      for (int e = 0; e < 4; e++) {
        const float tv = q[2 * e], sv = q[2 * e + 1];
        const int zi = 2 * e + par;
        z[zi] = z[zi] * expf(sv) + tv;
        ld[zi] += sv;
      }
    }
    __syncthreads();                          // TS reads done before next layer overwrites
  } // layer

  // ---- store z and log_det
  {
    float* zb = out + (size_t)(m0 + zr) * 64 + c0;
    float* lb = out + (size_t)NBATCH * 64 + (size_t)(m0 + zr) * 64 + c0;
    f32x4 v0, v1, l0, l1;
#pragma unroll
    for (int k = 0; k < 4; k++) {
      v0[k] = z[k]; v1[k] = z[4 + k];
      l0[k] = ld[k]; l1[k] = ld[4 + k];
    }
    *(f32x4*)&zb[0] = v0; *(f32x4*)&zb[4] = v1;
    *(f32x4*)&lb[0] = l0; *(f32x4*)&lb[4] = l1;
  }
}

extern "C" void kernel_launch(void* const* d_in, const int* in_sizes, int n_in,
                              void* d_out, int out_size, void* d_ws, size_t ws_size,
                              hipStream_t stream) {
  (void)in_sizes; (void)n_in; (void)out_size; (void)ws_size;
  const float* y   = (const float*)d_in[0];
  const float* tW1 = (const float*)d_in[1];
  const float* tb1 = (const float*)d_in[2];
  const float* tW2 = (const float*)d_in[3];
  const float* tb2 = (const float*)d_in[4];
  const float* tW3 = (const float*)d_in[5];
  const float* tb3 = (const float*)d_in[6];
  const float* sW1 = (const float*)d_in[7];
  const float* sb1 = (const float*)d_in[8];
  const float* sW2 = (const float*)d_in[9];
  const float* sb2 = (const float*)d_in[10];
  const float* sW3 = (const float*)d_in[11];
  const float* sb3 = (const float*)d_in[12];
  const float* s_scale = (const float*)d_in[13];
  const float* s_shift = (const float*)d_in[14];
  float* out = (float*)d_out;

  char* ws = (char*)d_ws;
  const size_t W1SZ = (size_t)16 * 512 * 32 * 2;    // 524288
  const size_t W2SZ = (size_t)16 * 512 * 512 * 2;   // 8388608
  u16* W1 = (u16*)(ws);
  u16* W2 = (u16*)(ws + W1SZ);
  u16* W3 = (u16*)(ws + W1SZ + W2SZ);

  cvt_w<<<dim3(16, 1, 16), dim3(32, 8), 0, stream>>>(tW1, sW1, W1, 32, 512);
  cvt_w<<<dim3(16, 16, 16), dim3(32, 8), 0, stream>>>(tW2, sW2, W2, 512, 512);
  cvt_w<<<dim3(1, 16, 16), dim3(32, 8), 0, stream>>>(tW3, sW3, W3, 512, 32);

  meganvp<<<256, 512, 0, stream>>>(y, W1, W2, W3, tb1, sb1, tb2, sb2, tb3, sb3,
                                   s_scale, s_shift, out);
}